// Round 15
// baseline (147.162 us; speedup 1.0000x reference)
//
#include <hip/hip_runtime.h>

#define N_NODES 100000
#define IN_F    256
#define OUT_F   256
#define BATCH   50000
#define NSAMP   25
#define K2      512
#define NTILE   1563    // ceil(100000/64)
#define XS      256     // persistent grid

typedef _Float16 f16_t;
typedef f16_t f16x8 __attribute__((ext_vector_type(8)));
typedef float f32x4 __attribute__((ext_vector_type(4)));
typedef float f32x2 __attribute__((ext_vector_type(2)));
typedef __bf16 bf16_t;
typedef bf16_t bf16x8 __attribute__((ext_vector_type(8)));

#if defined(__has_builtin)
#if __has_builtin(__builtin_amdgcn_cvt_pk_f32_fp8) && __has_builtin(__builtin_amdgcn_cvt_pk_fp8_f32)
#define FP8_HW 1
#endif
#endif
#ifndef FP8_HW
#include <hip/hip_fp8.h>
#endif

// workspace (bytes): Pself f16 [100000][256], Pneigh fp8 [100000][256], Wg f16 [512][256]
// F16 (f16 copy of features, 51.2 MB) lives in d_out — gather_add overwrites it later.
#define P8_OFF   51200000L
#define WG_OFF   76800000L
#define WS_NEED  (WG_OFF + 512L * 256 * 2)   // 77.06 MB

typedef __attribute__((address_space(1))) const unsigned int gas_uint;
typedef __attribute__((address_space(3))) unsigned int las_uint;

__device__ __forceinline__ void gll16(const void* g, void* l) {
    __builtin_amdgcn_global_load_lds((gas_uint*)g, (las_uint*)l, 16, 0, 0);
}

__device__ __forceinline__ float h2f(unsigned short u) {
    union { unsigned short u; f16_t h; } t; t.u = u; return (float)t.h;
}

__device__ __forceinline__ unsigned int pk_fp8x4(float a, float b, float c, float d) {
#ifdef FP8_HW
    unsigned int r = __builtin_amdgcn_cvt_pk_fp8_f32(a, b, 0u, false);
    r = __builtin_amdgcn_cvt_pk_fp8_f32(c, d, r, true);
    return r;
#else
    union { unsigned char b[4]; unsigned int u; } t;
    t.b[0] = __hip_fp8_e4m3(a).__x; t.b[1] = __hip_fp8_e4m3(b).__x;
    t.b[2] = __hip_fp8_e4m3(c).__x; t.b[3] = __hip_fp8_e4m3(d).__x;
    return t.u;
#endif
}

__device__ __forceinline__ void acc_fp8x4(unsigned int v, float4& a) {
#ifdef FP8_HW
    f32x2 lo = __builtin_amdgcn_cvt_pk_f32_fp8(v, false);
    f32x2 hi = __builtin_amdgcn_cvt_pk_f32_fp8(v, true);
    a.x += lo[0]; a.y += lo[1]; a.z += hi[0]; a.w += hi[1];
#else
    union { unsigned int u; unsigned char b[4]; } t; t.u = v;
    __hip_fp8_e4m3 e0, e1, e2, e3;
    e0.__x = t.b[0]; e1.__x = t.b[1]; e2.__x = t.b[2]; e3.__x = t.b[3];
    a.x += (float)e0; a.y += (float)e1; a.z += (float)e2; a.w += (float)e3;
#endif
}

// ---------------- Kernel A: F16 = (f16)features (into d_out scratch) ----------------
__global__ __launch_bounds__(256) void fcvt(const float* __restrict__ F,
                                            f16_t* __restrict__ F16) {
    const long n4 = (long)N_NODES * IN_F / 4;
    for (long i = (long)blockIdx.x * 256 + threadIdx.x; i < n4;
         i += (long)gridDim.x * 256) {
        float4 f = *(const float4*)&F[i * 4];
        union { ushort4 u; f16_t h[4]; } t;
        t.h[0] = (f16_t)f.x; t.h[1] = (f16_t)f.y;
        t.h[2] = (f16_t)f.z; t.h[3] = (f16_t)f.w;
        *(ushort4*)&F16[i * 4] = t.u;
    }
}

// ---------------- Kernel 0: rearrange W -> Wg[512][256] f16 ----------------
__global__ void wconv(const float* __restrict__ W, f16_t* __restrict__ Wg) {
    int idx = blockIdx.x * 256 + threadIdx.x;
    int j = idx >> 8, k = idx & 255;
    float v = (j < 256) ? W[j * K2 + k] : W[(j - 256) * K2 + 256 + k];
    Wg[idx] = (f16_t)v;
}

// ---------------- Kernel 1: P = F16 @ Wg^T (f16 MFMA, single-pass A) ----------------
// grid (256) persistent, 512 threads. Wave w owns 64 P-cols (w*64..w*64+63):
// waves 0-3 -> Pself f16, waves 4-7 -> Pneigh fp8. ALL 512 cols per block, so
// each A-tile (64 rows x 256 k f16, 32 KB) is staged ONCE (vs twice with the
// old y=2 grid): F16 FETCH halves, tiles/CU halves, LDS traffic halves.
// wgall[8][4] = 128 VGPR + acc[4][4] = 64 -> ~230 regs, inside the 256 budget
// of launch_bounds(512,2) (2 waves/EU) so no spill. bfr read once per k-step,
// reused by 4 ct-MFMAs (MFMA:ds_read = 4:1).
// vmcnt ladder (per-wave FIFO [stage4][stores16][stage4]): first 4, steady 20,
// tail 16 — epilogue stores never force-drained.
__global__ __launch_bounds__(512, 2) void proj_gemm(
    const f16_t* __restrict__ F16, const f16_t* __restrict__ Wg,
    f16_t* __restrict__ Pself, unsigned char* __restrict__ Pneigh8)
{
    __shared__ unsigned short buf[2][64 * 256];   // 2 x 32 KB f16 bits
    const int tid = threadIdx.x, lane = tid & 63, w = tid >> 6;   // w: 0..7
    const int q16 = lane >> 4, r16 = lane & 15;
    const int c0 = w * 64;                        // this wave's global P-col base

    // ---- hoist the wave's whole Wg slice: 8 k-steps x 4 col-frags = 128 VGPR ----
    f16x8 wgall[8][4];
    #pragma unroll
    for (int s = 0; s < 8; ++s)
        #pragma unroll
        for (int ct = 0; ct < 4; ++ct)
            wgall[s][ct] = *(const f16x8*)&Wg[(long)(c0 + ct * 16 + r16) * 256 + s * 32 + q16 * 8];

    f32x4 acc[4][4];
    #pragma unroll
    for (int ct = 0; ct < 4; ++ct)
        #pragma unroll
        for (int rt = 0; rt < 4; ++rt) acc[ct][rt] = (f32x4){0.f, 0.f, 0.f, 0.f};

    // stage one 64x256 f16 tile: 32 x 1KB chunks (2 rows each), 4 gll16/wave.
    // Pre-swizzled global source (rule 21): phys granule p holds logical p^(row&7).
#define STAGE(TT, BSEL)                                                         \
    {                                                                           \
        const long gr_ = (long)(TT) * 64;                                       \
        _Pragma("unroll")                                                       \
        for (int i_ = 0; i_ < 4; ++i_) {                                        \
            const int c_ = w * 4 + i_;                                          \
            const int row_ = 2 * c_ + (lane >> 5);                              \
            long srow_ = gr_ + row_; if (srow_ > N_NODES - 1) srow_ = N_NODES - 1; \
            const int g8_ = (((lane & 31) ^ (row_ & 7)) * 8);                   \
            gll16(&F16[srow_ * 256 + g8_], &buf[BSEL][c_ * 512]);               \
        }                                                                       \
    }

    STAGE(blockIdx.x, 0);
    int cur = 0;
    bool first = true;

    for (int t = blockIdx.x; t < NTILE; t += XS) {
        __builtin_amdgcn_s_barrier();          // all waves done reading buf[cur^1]
        const int nt = t + XS;
        if (nt < NTILE) {
            STAGE(nt, cur ^ 1);
            if (first) asm volatile("s_waitcnt vmcnt(4)" ::: "memory");
            else       asm volatile("s_waitcnt vmcnt(20)" ::: "memory");
        } else {
            asm volatile("s_waitcnt vmcnt(16)" ::: "memory");
        }
        __builtin_amdgcn_sched_barrier(0);
        __builtin_amdgcn_s_barrier();          // buf[cur] fully landed
        first = false;

        // ---- compute: ds_read_b128 once, 4 MFMAs per fragment ----
        #pragma unroll
        for (int sg = 0; sg < 8; ++sg) {
            f16x8 bfr[4];
            #pragma unroll
            for (int rt = 0; rt < 4; ++rt) {
                const int row = rt * 16 + r16;
                const int g   = (sg * 4 + q16) ^ (row & 7);
                bfr[rt] = *(const f16x8*)&buf[cur][row * 256 + g * 8];
            }
            #pragma unroll
            for (int ct = 0; ct < 4; ++ct)
                #pragma unroll
                for (int rt = 0; rt < 4; ++rt)
                    acc[ct][rt] = __builtin_amdgcn_mfma_f32_16x16x32_f16(
                        wgall[sg][ct], bfr[rt], acc[ct][rt], 0, 0, 0);
        }

        // ---- epilogue for tile t (16 stores/wave) ----
        const long gr0 = (long)t * 64;
        if (w < 4) {
            #pragma unroll
            for (int rt = 0; rt < 4; ++rt) {
                const long row = gr0 + rt * 16 + r16;
                const bool ok = row < N_NODES;
                #pragma unroll
                for (int ct = 0; ct < 4; ++ct) {
                    const int colb = c0 + ct * 16 + q16 * 4;
                    if (ok) {
                        union { ushort4 u; f16_t hh[4]; } tt;
                        tt.hh[0] = (f16_t)acc[ct][rt][0]; tt.hh[1] = (f16_t)acc[ct][rt][1];
                        tt.hh[2] = (f16_t)acc[ct][rt][2]; tt.hh[3] = (f16_t)acc[ct][rt][3];
                        *(ushort4*)&Pself[row * 256 + colb] = tt.u;
                    }
                }
            }
        } else {
            #pragma unroll
            for (int rt = 0; rt < 4; ++rt) {
                const long row = gr0 + rt * 16 + r16;
                const bool ok = row < N_NODES;
                #pragma unroll
                for (int ct = 0; ct < 4; ++ct) {
                    const int colb = (c0 - 256) + ct * 16 + q16 * 4;
                    unsigned int pk = pk_fp8x4(acc[ct][rt][0], acc[ct][rt][1],
                                               acc[ct][rt][2], acc[ct][rt][3]);
                    if (ok) *(unsigned int*)&Pneigh8[row * 256 + colb] = pk;
                }
            }
        }
        #pragma unroll
        for (int ct = 0; ct < 4; ++ct)
            #pragma unroll
            for (int rt = 0; rt < 4; ++rt) acc[ct][rt] = (f32x4){0.f, 0.f, 0.f, 0.f};
        cur ^= 1;
    }
#undef STAGE
}

// ---------------- Kernel 2: out[b] = Pself[ni[b]] + mean_s fp8(Pneigh[nb[b,s]]) ----------------
__global__ __launch_bounds__(256) void gather_add(
    const f16_t* __restrict__ Pself, const unsigned char* __restrict__ P8,
    const int* __restrict__ node_idx, const int* __restrict__ neigh_idx,
    float* __restrict__ out)
{
    const int tid = threadIdx.x, lane = tid & 63, w = tid >> 6;
    const long b0 = (long)blockIdx.x * 8 + w * 2;
    const int c4 = lane * 4;

    int ns0[NSAMP], ns1[NSAMP];
    #pragma unroll
    for (int s = 0; s < NSAMP; ++s) ns0[s] = neigh_idx[b0 * NSAMP + s];
    #pragma unroll
    for (int s = 0; s < NSAMP; ++s) ns1[s] = neigh_idx[(b0 + 1) * NSAMP + s];
    const int sn0 = node_idx[b0], sn1 = node_idx[b0 + 1];

    const ushort4 sv0 = *(const ushort4*)&Pself[(long)sn0 * 256 + c4];
    const ushort4 sv1 = *(const ushort4*)&Pself[(long)sn1 * 256 + c4];

    unsigned int v0[NSAMP], v1[NSAMP];
    #pragma unroll
    for (int s = 0; s < NSAMP; ++s)
        v0[s] = *(const unsigned int*)&P8[(long)ns0[s] * 256 + c4];
    #pragma unroll
    for (int s = 0; s < NSAMP; ++s)
        v1[s] = *(const unsigned int*)&P8[(long)ns1[s] * 256 + c4];

    float4 a0 = make_float4(0.f, 0.f, 0.f, 0.f);
    float4 a1 = make_float4(0.f, 0.f, 0.f, 0.f);
    #pragma unroll
    for (int s = 0; s < NSAMP; ++s) acc_fp8x4(v0[s], a0);
    #pragma unroll
    for (int s = 0; s < NSAMP; ++s) acc_fp8x4(v1[s], a1);

    const float inv = 1.0f / (float)NSAMP;
    float4 o0, o1;
    o0.x = h2f(sv0.x) + a0.x * inv; o0.y = h2f(sv0.y) + a0.y * inv;
    o0.z = h2f(sv0.z) + a0.z * inv; o0.w = h2f(sv0.w) + a0.w * inv;
    o1.x = h2f(sv1.x) + a1.x * inv; o1.y = h2f(sv1.y) + a1.y * inv;
    o1.z = h2f(sv1.z) + a1.z * inv; o1.w = h2f(sv1.w) + a1.w * inv;
    *(float4*)&out[b0 * OUT_F + c4] = o0;
    *(float4*)&out[(b0 + 1) * OUT_F + c4] = o1;
}

// ---------------- Fallback (monolithic) if ws too small ----------------
__device__ __forceinline__ int swz_bf(int row, int us_idx) {
    return us_idx ^ ((row & 7) << 3);
}
__device__ __forceinline__ void store_bf4(unsigned short* comb, int r, int col, float4 f) {
    union { ushort4 u; bf16_t b[4]; } t;
    t.b[0] = (bf16_t)f.x; t.b[1] = (bf16_t)f.y;
    t.b[2] = (bf16_t)f.z; t.b[3] = (bf16_t)f.w;
    *(ushort4*)&comb[swz_bf(r, r * K2 + col)] = t.u;
}
__global__ __launch_bounds__(256, 4) void sage_fused(
    const float* __restrict__ features, const int* __restrict__ node_idx,
    const int* __restrict__ neigh_idx, const float* __restrict__ W,
    float* __restrict__ out)
{
    __shared__ unsigned short comb[16 * K2];
    const int tid = threadIdx.x, lane = tid & 63, wy = tid >> 6;
    const int b0 = blockIdx.x * 16;
    const int col4 = lane * 4;
    #pragma unroll
    for (int i = 0; i < 4; ++i) {
        const int r = wy * 4 + i;
        const long b = b0 + r;
        int nidx[NSAMP];
        #pragma unroll
        for (int s = 0; s < NSAMP; ++s) nidx[s] = neigh_idx[b * NSAMP + s];
        const int self_n = node_idx[b];
        const float4 sf = *(const float4*)&features[(long)self_n * IN_F + col4];
        float4 v[13];
        #pragma unroll
        for (int s = 0; s < 13; ++s)
            v[s] = *(const float4*)&features[(long)nidx[s] * IN_F + col4];
        float4 acc = v[0];
        #pragma unroll
        for (int s = 1; s < 13; ++s) {
            acc.x += v[s].x; acc.y += v[s].y; acc.z += v[s].z; acc.w += v[s].w;
        }
        #pragma unroll
        for (int s = 13; s < NSAMP; ++s)
            v[s - 13] = *(const float4*)&features[(long)nidx[s] * IN_F + col4];
        #pragma unroll
        for (int s = 0; s < 12; ++s) {
            acc.x += v[s].x; acc.y += v[s].y; acc.z += v[s].z; acc.w += v[s].w;
        }
        const float inv = 1.0f / (float)NSAMP;
        acc.x *= inv; acc.y *= inv; acc.z *= inv; acc.w *= inv;
        store_bf4(comb, r, col4, sf);
        store_bf4(comb, r, IN_F + col4, acc);
    }
    __syncthreads();
    const int c0 = wy * 64, arow = lane & 15, kq = (lane >> 4) * 8;
    f32x4 acc[4];
    #pragma unroll
    for (int t = 0; t < 4; ++t) acc[t] = (f32x4){0.f, 0.f, 0.f, 0.f};
    #pragma unroll
    for (int ks = 0; ks < 16; ++ks) {
        const int kb = ks * 32 + kq;
        const bf16x8 af = *(const bf16x8*)&comb[swz_bf(arow, arow * K2 + kb)];
        #pragma unroll
        for (int t = 0; t < 4; ++t) {
            const float* wp = &W[(long)(c0 + t * 16 + arow) * K2 + kb];
            const float4 w0 = *(const float4*)wp;
            const float4 w1 = *(const float4*)(wp + 4);
            bf16x8 bf;
            bf[0] = (bf16_t)w0.x; bf[1] = (bf16_t)w0.y;
            bf[2] = (bf16_t)w0.z; bf[3] = (bf16_t)w0.w;
            bf[4] = (bf16_t)w1.x; bf[5] = (bf16_t)w1.y;
            bf[6] = (bf16_t)w1.z; bf[7] = (bf16_t)w1.w;
            acc[t] = __builtin_amdgcn_mfma_f32_16x16x32_bf16(af, bf, acc[t], 0, 0, 0);
        }
    }
    #pragma unroll
    for (int t = 0; t < 4; ++t) {
        const int col = c0 + t * 16 + arow;
        #pragma unroll
        for (int j = 0; j < 4; ++j) {
            const int row = b0 + (lane >> 4) * 4 + j;
            out[(long)row * OUT_F + col] = acc[t][j];
        }
    }
}

extern "C" void kernel_launch(void* const* d_in, const int* in_sizes, int n_in,
                              void* d_out, int out_size, void* d_ws, size_t ws_size,
                              hipStream_t stream) {
    const float* features  = (const float*)d_in[0];
    const int*   node_idx  = (const int*)d_in[1];
    const int*   neigh_idx = (const int*)d_in[2];
    const float* W         = (const float*)d_in[3];
    float*       out       = (float*)d_out;

    if (ws_size >= (size_t)WS_NEED) {
        f16_t*         Pself  = (f16_t*)d_ws;
        unsigned char* P8     = (unsigned char*)d_ws + P8_OFF;
        f16_t*         Wg     = (f16_t*)((char*)d_ws + WG_OFF);
        f16_t*         F16    = (f16_t*)d_out;   // d_out as scratch; gather overwrites
        fcvt<<<2048, 256, 0, stream>>>(features, F16);
        wconv<<<512, 256, 0, stream>>>(W, Wg);
        proj_gemm<<<XS, 512, 0, stream>>>(F16, Wg, Pself, P8);
        gather_add<<<BATCH / 8, 256, 0, stream>>>(Pself, P8, node_idx, neigh_idx, out);
    } else {
        sage_fused<<<BATCH / 16, 256, 0, stream>>>(features, node_idx, neigh_idx, W, out);
    }
}

// Round 16
// 125.602 us; speedup vs baseline: 1.1717x; 1.1717x over previous
//
#include <hip/hip_runtime.h>

#define N_NODES 100000
#define IN_F    256
#define OUT_F   256
#define BATCH   50000
#define NSAMP   25
#define K2      512
#define NTILE   1563    // ceil(100000/64)
#define XS      256     // persistent grid x

typedef _Float16 f16_t;
typedef f16_t f16x8 __attribute__((ext_vector_type(8)));
typedef float f32x4 __attribute__((ext_vector_type(4)));
typedef float f32x2 __attribute__((ext_vector_type(2)));
typedef __bf16 bf16_t;
typedef bf16_t bf16x8 __attribute__((ext_vector_type(8)));

#if defined(__has_builtin)
#if __has_builtin(__builtin_amdgcn_cvt_pk_f32_fp8) && __has_builtin(__builtin_amdgcn_cvt_pk_fp8_f32)
#define FP8_HW 1
#endif
#endif
#ifndef FP8_HW
#include <hip/hip_fp8.h>
#endif

// workspace (bytes): Pself f16 [100000][256], Pneigh fp8 [100000][256], Wg f16 [512][256]
#define P8_OFF   51200000L
#define WG_OFF   76800000L
#define WS_NEED  (WG_OFF + 512L * 256 * 2)

__device__ __forceinline__ float h2f(unsigned short u) {
    union { unsigned short u; f16_t h; } t; t.u = u; return (float)t.h;
}

__device__ __forceinline__ unsigned int pk_fp8x4(float a, float b, float c, float d) {
#ifdef FP8_HW
    unsigned int r = __builtin_amdgcn_cvt_pk_fp8_f32(a, b, 0u, false);
    r = __builtin_amdgcn_cvt_pk_fp8_f32(c, d, r, true);
    return r;
#else
    union { unsigned char b[4]; unsigned int u; } t;
    t.b[0] = __hip_fp8_e4m3(a).__x; t.b[1] = __hip_fp8_e4m3(b).__x;
    t.b[2] = __hip_fp8_e4m3(c).__x; t.b[3] = __hip_fp8_e4m3(d).__x;
    return t.u;
#endif
}

__device__ __forceinline__ void acc_fp8x4(unsigned int v, float4& a) {
#ifdef FP8_HW
    f32x2 lo = __builtin_amdgcn_cvt_pk_f32_fp8(v, false);
    f32x2 hi = __builtin_amdgcn_cvt_pk_f32_fp8(v, true);
    a.x += lo[0]; a.y += lo[1]; a.z += hi[0]; a.w += hi[1];
#else
    union { unsigned int u; unsigned char b[4]; } t; t.u = v;
    __hip_fp8_e4m3 e0, e1, e2, e3;
    e0.__x = t.b[0]; e1.__x = t.b[1]; e2.__x = t.b[2]; e3.__x = t.b[3];
    a.x += (float)e0; a.y += (float)e1; a.z += (float)e2; a.w += (float)e3;
#endif
}

// ---------------- Kernel 0: rearrange W -> Wg[512][256] f16 ----------------
__global__ void wconv(const float* __restrict__ W, f16_t* __restrict__ Wg) {
    int idx = blockIdx.x * 256 + threadIdx.x;
    int j = idx >> 8, k = idx & 255;
    float v = (j < 256) ? W[j * K2 + k] : W[(j - 256) * K2 + 256 + k];
    Wg[idx] = (f16_t)v;
}

// ---------------- Kernel 1: P = F @ Wg^T (f16 MFMA, phase-interleaved) ----------------
// R13 base (fused fp32->f16 staging, grid (256,2) persistent, 512 threads,
// one __syncthreads per tile, dbuf f16 LDS A-tile, wgall[8][2] in regs) with
// the compute restructured into 4 PHASES per tile. Phase p:
//   - ds_read the 8 fragments for k-steps 2p,2p+1
//   - p<2: issue next tile's global loads (2 chunks of v)
//   - p>=2: cvt+swizzled ds_write next tile's chunks into buf[cur^1]
//     (loads from p0/p1 have had >=2 phases to land; compiler inserts vmcnt)
//   - setprio(1); 16 MFMA; setprio(0)
// This feeds the memory pipes DURING the MFMA stream instead of bunching all
// staging at the barrier (m233-style 2-phase stall was the diagnosis).
// Dbuf race-safety: ds_writes target buf[cur^1] only; reads target buf[cur];
// one barrier per tile orders the swap (same invariant as R13).
__global__ __launch_bounds__(512, 2) void proj_gemm(
    const float* __restrict__ features, const f16_t* __restrict__ Wg,
    f16_t* __restrict__ Pself, unsigned char* __restrict__ Pneigh8)
{
    __shared__ unsigned short buf[2][64 * 256];   // 2 x 32 KB f16 bits
    const int tid = threadIdx.x, lane = tid & 63, w = tid >> 6;   // w: 0..7
    const int q16 = lane >> 4, r16 = lane & 15;
    const int c0 = blockIdx.y * 256 + w * 32;     // this wave's global P-col base
    const int row_s = tid >> 3;                   // staging row (0..63)
    const int seg_s = tid & 7;                    // staging segment (32 f32)

    // ---- Wg slice in regs: 8 k-steps x 2 col-frags = 64 VGPR, static index ----
    f16x8 wgall[8][2];
    #pragma unroll
    for (int s = 0; s < 8; ++s)
        #pragma unroll
        for (int ct = 0; ct < 2; ++ct)
            wgall[s][ct] = *(const f16x8*)&Wg[(long)(c0 + ct * 16 + r16) * 256 + s * 32 + q16 * 8];

    f32x4 acc[2][4];
    #pragma unroll
    for (int ct = 0; ct < 2; ++ct)
        #pragma unroll
        for (int rt = 0; rt < 4; ++rt) acc[ct][rt] = (f32x4){0.f, 0.f, 0.f, 0.f};

    float4 v[8];   // staged fp32 (thread's 32 consecutive cols of one row)

    // load chunk c (v[2c], v[2c+1]) of tile TT
#define VLOAD_CHUNK(TT, C)                                                      \
    {                                                                           \
        long sr_ = (long)(TT) * 64 + row_s;                                     \
        if (sr_ > N_NODES - 1) sr_ = N_NODES - 1;                               \
        const float* p_ = &features[sr_ * IN_F + seg_s * 32 + (C) * 8];         \
        v[2 * (C)]     = *(const float4*)(p_);                                  \
        v[2 * (C) + 1] = *(const float4*)(p_ + 4);                              \
    }

    // cvt + swizzled ds_write of chunk c into buf[BSEL]
#define CVT_CHUNK(BSEL, C)                                                      \
    {                                                                           \
        const int g_  = seg_s * 4 + (C);                                        \
        const int gp_ = g_ ^ (row_s & 7);                                       \
        f16x8 hh_;                                                              \
        hh_[0] = (f16_t)v[2 * (C)].x;     hh_[1] = (f16_t)v[2 * (C)].y;         \
        hh_[2] = (f16_t)v[2 * (C)].z;     hh_[3] = (f16_t)v[2 * (C)].w;         \
        hh_[4] = (f16_t)v[2 * (C) + 1].x; hh_[5] = (f16_t)v[2 * (C) + 1].y;     \
        hh_[6] = (f16_t)v[2 * (C) + 1].z; hh_[7] = (f16_t)v[2 * (C) + 1].w;     \
        *(f16x8*)&buf[BSEL][row_s * 256 + gp_ * 8] = hh_;                       \
    }

    // prologue: stage tile bx into buf[0]
    #pragma unroll
    for (int c = 0; c < 4; ++c) VLOAD_CHUNK(blockIdx.x, c);
    #pragma unroll
    for (int c = 0; c < 4; ++c) CVT_CHUNK(0, c);
    __syncthreads();
    int cur = 0;

    for (int t = blockIdx.x; t < NTILE; t += XS) {
        const int nt = t + XS;
        const bool hn = nt < NTILE;

        // ---- 4 phases: {ds_read 2 k-steps | stage-interleave | 16 MFMA} ----
        #pragma unroll
        for (int p = 0; p < 4; ++p) {
            f16x8 bfr[2][4];
            #pragma unroll
            for (int shalf = 0; shalf < 2; ++shalf) {
                const int sg = 2 * p + shalf;
                #pragma unroll
                for (int rt = 0; rt < 4; ++rt) {
                    const int row = rt * 16 + r16;
                    const int g   = (sg * 4 + q16) ^ (row & 7);
                    bfr[shalf][rt] = *(const f16x8*)&buf[cur][row * 256 + g * 8];
                }
            }
            if (hn) {
                if (p < 2) {            // issue next tile's loads early
                    VLOAD_CHUNK(nt, 2 * p);
                    VLOAD_CHUNK(nt, 2 * p + 1);
                } else {                // convert+write after >=2 phases of latency
                    CVT_CHUNK(cur ^ 1, 2 * (p - 2));
                    CVT_CHUNK(cur ^ 1, 2 * (p - 2) + 1);
                }
            }
            __builtin_amdgcn_s_setprio(1);
            #pragma unroll
            for (int shalf = 0; shalf < 2; ++shalf) {
                const int sg = 2 * p + shalf;
                #pragma unroll
                for (int ct = 0; ct < 2; ++ct)
                    #pragma unroll
                    for (int rt = 0; rt < 4; ++rt)
                        acc[ct][rt] = __builtin_amdgcn_mfma_f32_16x16x32_f16(
                            wgall[sg][ct], bfr[shalf][rt], acc[ct][rt], 0, 0, 0);
            }
            __builtin_amdgcn_s_setprio(0);
        }

        // ---- epilogue for tile t ----
        const long gr0 = (long)t * 64;
        if (blockIdx.y == 0) {
            #pragma unroll
            for (int rt = 0; rt < 4; ++rt) {
                const long row = gr0 + rt * 16 + r16;
                const bool ok = row < N_NODES;
                #pragma unroll
                for (int ct = 0; ct < 2; ++ct) {
                    const int colb = w * 32 + ct * 16 + q16 * 4;
                    if (ok) {
                        union { ushort4 u; f16_t hh[4]; } tt;
                        tt.hh[0] = (f16_t)acc[ct][rt][0]; tt.hh[1] = (f16_t)acc[ct][rt][1];
                        tt.hh[2] = (f16_t)acc[ct][rt][2]; tt.hh[3] = (f16_t)acc[ct][rt][3];
                        *(ushort4*)&Pself[row * 256 + colb] = tt.u;
                    }
                }
            }
        } else {
            #pragma unroll
            for (int rt = 0; rt < 4; ++rt) {
                const long row = gr0 + rt * 16 + r16;
                const bool ok = row < N_NODES;
                #pragma unroll
                for (int ct = 0; ct < 2; ++ct) {
                    const int colb = w * 32 + ct * 16 + q16 * 4;
                    unsigned int pk = pk_fp8x4(acc[ct][rt][0], acc[ct][rt][1],
                                               acc[ct][rt][2], acc[ct][rt][3]);
                    if (ok) *(unsigned int*)&Pneigh8[row * 256 + colb] = pk;
                }
            }
        }
        #pragma unroll
        for (int ct = 0; ct < 2; ++ct)
            #pragma unroll
            for (int rt = 0; rt < 4; ++rt) acc[ct][rt] = (f32x4){0.f, 0.f, 0.f, 0.f};

        __syncthreads();     // buf[cur^1] fully written; safe to swap
        cur ^= 1;
    }
#undef VLOAD_CHUNK
#undef CVT_CHUNK
}

// ---------------- Kernel 2: out[b] = Pself[ni[b]] + mean_s fp8(Pneigh[nb[b,s]]) ----------------
__global__ __launch_bounds__(256) void gather_add(
    const f16_t* __restrict__ Pself, const unsigned char* __restrict__ P8,
    const int* __restrict__ node_idx, const int* __restrict__ neigh_idx,
    float* __restrict__ out)
{
    const int tid = threadIdx.x, lane = tid & 63, w = tid >> 6;
    const long b0 = (long)blockIdx.x * 8 + w * 2;
    const int c4 = lane * 4;

    int ns0[NSAMP], ns1[NSAMP];
    #pragma unroll
    for (int s = 0; s < NSAMP; ++s) ns0[s] = neigh_idx[b0 * NSAMP + s];
    #pragma unroll
    for (int s = 0; s < NSAMP; ++s) ns1[s] = neigh_idx[(b0 + 1) * NSAMP + s];
    const int sn0 = node_idx[b0], sn1 = node_idx[b0 + 1];

    const ushort4 sv0 = *(const ushort4*)&Pself[(long)sn0 * 256 + c4];
    const ushort4 sv1 = *(const ushort4*)&Pself[(long)sn1 * 256 + c4];

    unsigned int v0[NSAMP], v1[NSAMP];
    #pragma unroll
    for (int s = 0; s < NSAMP; ++s)
        v0[s] = *(const unsigned int*)&P8[(long)ns0[s] * 256 + c4];
    #pragma unroll
    for (int s = 0; s < NSAMP; ++s)
        v1[s] = *(const unsigned int*)&P8[(long)ns1[s] * 256 + c4];

    float4 a0 = make_float4(0.f, 0.f, 0.f, 0.f);
    float4 a1 = make_float4(0.f, 0.f, 0.f, 0.f);
    #pragma unroll
    for (int s = 0; s < NSAMP; ++s) acc_fp8x4(v0[s], a0);
    #pragma unroll
    for (int s = 0; s < NSAMP; ++s) acc_fp8x4(v1[s], a1);

    const float inv = 1.0f / (float)NSAMP;
    float4 o0, o1;
    o0.x = h2f(sv0.x) + a0.x * inv; o0.y = h2f(sv0.y) + a0.y * inv;
    o0.z = h2f(sv0.z) + a0.z * inv; o0.w = h2f(sv0.w) + a0.w * inv;
    o1.x = h2f(sv1.x) + a1.x * inv; o1.y = h2f(sv1.y) + a1.y * inv;
    o1.z = h2f(sv1.z) + a1.z * inv; o1.w = h2f(sv1.w) + a1.w * inv;
    *(float4*)&out[b0 * OUT_F + c4] = o0;
    *(float4*)&out[(b0 + 1) * OUT_F + c4] = o1;
}

// ---------------- Fallback (monolithic) if ws too small ----------------
__device__ __forceinline__ int swz_bf(int row, int us_idx) {
    return us_idx ^ ((row & 7) << 3);
}
__device__ __forceinline__ void store_bf4(unsigned short* comb, int r, int col, float4 f) {
    union { ushort4 u; bf16_t b[4]; } t;
    t.b[0] = (bf16_t)f.x; t.b[1] = (bf16_t)f.y;
    t.b[2] = (bf16_t)f.z; t.b[3] = (bf16_t)f.w;
    *(ushort4*)&comb[swz_bf(r, r * K2 + col)] = t.u;
}
__global__ __launch_bounds__(256, 4) void sage_fused(
    const float* __restrict__ features, const int* __restrict__ node_idx,
    const int* __restrict__ neigh_idx, const float* __restrict__ W,
    float* __restrict__ out)
{
    __shared__ unsigned short comb[16 * K2];
    const int tid = threadIdx.x, lane = tid & 63, wy = tid >> 6;
    const int b0 = blockIdx.x * 16;
    const int col4 = lane * 4;
    #pragma unroll
    for (int i = 0; i < 4; ++i) {
        const int r = wy * 4 + i;
        const long b = b0 + r;
        int nidx[NSAMP];
        #pragma unroll
        for (int s = 0; s < NSAMP; ++s) nidx[s] = neigh_idx[b * NSAMP + s];
        const int self_n = node_idx[b];
        const float4 sf = *(const float4*)&features[(long)self_n * IN_F + col4];
        float4 v[13];
        #pragma unroll
        for (int s = 0; s < 13; ++s)
            v[s] = *(const float4*)&features[(long)nidx[s] * IN_F + col4];
        float4 acc = v[0];
        #pragma unroll
        for (int s = 1; s < 13; ++s) {
            acc.x += v[s].x; acc.y += v[s].y; acc.z += v[s].z; acc.w += v[s].w;
        }
        #pragma unroll
        for (int s = 13; s < NSAMP; ++s)
            v[s - 13] = *(const float4*)&features[(long)nidx[s] * IN_F + col4];
        #pragma unroll
        for (int s = 0; s < 12; ++s) {
            acc.x += v[s].x; acc.y += v[s].y; acc.z += v[s].z; acc.w += v[s].w;
        }
        const float inv = 1.0f / (float)NSAMP;
        acc.x *= inv; acc.y *= inv; acc.z *= inv; acc.w *= inv;
        store_bf4(comb, r, col4, sf);
        store_bf4(comb, r, IN_F + col4, acc);
    }
    __syncthreads();
    const int c0 = wy * 64, arow = lane & 15, kq = (lane >> 4) * 8;
    f32x4 acc[4];
    #pragma unroll
    for (int t = 0; t < 4; ++t) acc[t] = (f32x4){0.f, 0.f, 0.f, 0.f};
    #pragma unroll
    for (int ks = 0; ks < 16; ++ks) {
        const int kb = ks * 32 + kq;
        const bf16x8 af = *(const bf16x8*)&comb[swz_bf(arow, arow * K2 + kb)];
        #pragma unroll
        for (int t = 0; t < 4; ++t) {
            const float* wp = &W[(long)(c0 + t * 16 + arow) * K2 + kb];
            const float4 w0 = *(const float4*)wp;
            const float4 w1 = *(const float4*)(wp + 4);
            bf16x8 bf;
            bf[0] = (bf16_t)w0.x; bf[1] = (bf16_t)w0.y;
            bf[2] = (bf16_t)w0.z; bf[3] = (bf16_t)w0.w;
            bf[4] = (bf16_t)w1.x; bf[5] = (bf16_t)w1.y;
            bf[6] = (bf16_t)w1.z; bf[7] = (bf16_t)w1.w;
            acc[t] = __builtin_amdgcn_mfma_f32_16x16x32_bf16(af, bf, acc[t], 0, 0, 0);
        }
    }
    #pragma unroll
    for (int t = 0; t < 4; ++t) {
        const int col = c0 + t * 16 + arow;
        #pragma unroll
        for (int j = 0; j < 4; ++j) {
            const int row = b0 + (lane >> 4) * 4 + j;
            out[(long)row * OUT_F + col] = acc[t][j];
        }
    }
}

extern "C" void kernel_launch(void* const* d_in, const int* in_sizes, int n_in,
                              void* d_out, int out_size, void* d_ws, size_t ws_size,
                              hipStream_t stream) {
    const float* features  = (const float*)d_in[0];
    const int*   node_idx  = (const int*)d_in[1];
    const int*   neigh_idx = (const int*)d_in[2];
    const float* W         = (const float*)d_in[3];
    float*       out       = (float*)d_out;

    if (ws_size >= (size_t)WS_NEED) {
        f16_t*         Pself  = (f16_t*)d_ws;
        unsigned char* P8     = (unsigned char*)d_ws + P8_OFF;
        f16_t*         Wg     = (f16_t*)((char*)d_ws + WG_OFF);
        wconv<<<512, 256, 0, stream>>>(W, Wg);
        proj_gemm<<<dim3(XS, 2), 512, 0, stream>>>(features, Wg, Pself, P8);
        gather_add<<<BATCH / 8, 256, 0, stream>>>(Pself, P8, node_idx, neigh_idx, out);
    } else {
        sage_fused<<<BATCH / 16, 256, 0, stream>>>(features, node_idx, neigh_idx, W, out);
    }
}